// Round 15
// baseline (560.612 us; speedup 1.0000x reference)
//
#include <hip/hip_runtime.h>

using u16 = unsigned short;
using u32 = unsigned int;

constexpr int Bn   = 256;
constexpr int Dd   = 1280;
constexpr int Cc   = 64;
constexpr int WINc = 14;
constexpr int NHc  = 8;
constexpr int Ac   = 49;
constexpr int Nc   = WINc * WINc;   // 196
constexpr int HDc  = Cc / NHc;      // 8
constexpr int B3c  = 3 * Bn;        // 768
constexpr int CNc  = Cc * Nc;       // 12544

typedef __attribute__((ext_vector_type(8))) short v8s;   // 8 bf16 = 4 VGPRs
typedef __attribute__((ext_vector_type(4))) float v4f;
typedef __attribute__((ext_vector_type(2))) float v2f;   // packed fp32 (v_pk_*)

// bf16 helpers: inputs fp32, workspace intermediates bf16, OUTPUT fp32.
__device__ __forceinline__ float bflo(u32 u){ union{u32 x; float f;} c; c.x = u << 16; return c.f; }
__device__ __forceinline__ float bfhi(u32 u){ union{u32 x; float f;} c; c.x = u & 0xffff0000u; return c.f; }
__device__ __forceinline__ float bfs(u16 h){ union{u32 x; float f;} c; c.x = ((u32)h) << 16; return c.f; }
__device__ __forceinline__ u16 f2bb(float f){
  u32 u = __float_as_uint(f);
  u32 r = (u + 0x7fffu + ((u >> 16) & 1u)) >> 16;
  return (u16)r;
}
__device__ __forceinline__ void unpack8(uint4 u, float* dst){
  dst[0]=bflo(u.x); dst[1]=bfhi(u.x); dst[2]=bflo(u.y); dst[3]=bfhi(u.y);
  dst[4]=bflo(u.z); dst[5]=bfhi(u.z); dst[6]=bflo(u.w); dst[7]=bfhi(u.w);
}
__device__ __forceinline__ uint4 pack8(const float* s){
  uint4 r;
  r.x = (u32)f2bb(s[0]) | ((u32)f2bb(s[1]) << 16);
  r.y = (u32)f2bb(s[2]) | ((u32)f2bb(s[3]) << 16);
  r.z = (u32)f2bb(s[4]) | ((u32)f2bb(s[5]) << 16);
  r.w = (u32)f2bb(s[6]) | ((u32)f2bb(s[7]) << 16);
  return r;
}

// ---------------------------------------------------------------------------
// One-time fp32->bf16 conversion of W_embed, X, W_adj (unchanged, passing).
// ---------------------------------------------------------------------------
constexpr int WeN   = 12544 * 1280;   // 16,056,320
constexpr int XN    = 768 * 1280;     //    983,040
constexpr int WadjN = 256 * CNc;      //  3,211,264
__global__ __launch_bounds__(256) void conv_bf16_kernel(const float* __restrict__ We,
                                                        const float* __restrict__ X,
                                                        const float* __restrict__ Wadj,
                                                        u16* __restrict__ WeB,
                                                        u16* __restrict__ XB,
                                                        u16* __restrict__ WadjB)
{
  const size_t idx = ((size_t)blockIdx.x * 256 + threadIdx.x) * 8;
  const float* src; u16* dst;
  if (idx < (size_t)WeN)            { src = We + idx;               dst = WeB + idx; }
  else if (idx < (size_t)WeN + XN)  { src = X + (idx - WeN);        dst = XB + (idx - WeN); }
  else                              { src = Wadj + (idx - WeN - XN); dst = WadjB + (idx - WeN - XN); }
  float v[8];
  *reinterpret_cast<float4*>(&v[0]) = *reinterpret_cast<const float4*>(src);
  *reinterpret_cast<float4*>(&v[4]) = *reinterpret_cast<const float4*>(src + 4);
  *reinterpret_cast<uint4*>(dst) = pack8(v);
}

// ---------------------------------------------------------------------------
// embed GEMM, all-bf16 inputs (unchanged, passing).
// ---------------------------------------------------------------------------
__global__ __launch_bounds__(256) void gemm_embed_bf16(const u16* __restrict__ Amat,
                                                       const u16* __restrict__ Bmat,
                                                       const float* __restrict__ bias,
                                                       u16* __restrict__ Cmat)
{
  constexpr int K = Dd, Nn = CNc;
  __shared__ u16 As[128 * 40];
  __shared__ u16 Bs[128 * 40];
  const int t = threadIdx.x;
  const int n0 = blockIdx.x * 128, m0 = blockIdx.y * 128;   // n fastest
  const int wave = t >> 6, lane = t & 63;
  const int wm = wave >> 1, wn = wave & 1;
  const int mi = lane & 15, quad = lane >> 4;

  v4f acc[4][4];
  #pragma unroll
  for (int a = 0; a < 4; ++a)
    #pragma unroll
    for (int b = 0; b < 4; ++b) acc[a][b] = (v4f){0.f, 0.f, 0.f, 0.f};

  const int srow = t >> 1, scol = (t & 1) * 16;
  const u16* apb = Amat + (size_t)(m0 + srow) * K + scol;
  const u16* bpb = Bmat + (size_t)(n0 + srow) * K + scol;

  uint4 a0 = *reinterpret_cast<const uint4*>(apb);
  uint4 a1 = *reinterpret_cast<const uint4*>(apb + 8);
  uint4 b0 = *reinterpret_cast<const uint4*>(bpb);
  uint4 b1 = *reinterpret_cast<const uint4*>(bpb + 8);

  for (int kt = 0; kt < K; kt += 32) {
    *reinterpret_cast<uint4*>(&As[srow*40 + scol])     = a0;
    *reinterpret_cast<uint4*>(&As[srow*40 + scol + 8]) = a1;
    *reinterpret_cast<uint4*>(&Bs[srow*40 + scol])     = b0;
    *reinterpret_cast<uint4*>(&Bs[srow*40 + scol + 8]) = b1;
    __syncthreads();

    const int kn = (kt + 32 < K) ? kt + 32 : 0;   // clamped prefetch
    a0 = *reinterpret_cast<const uint4*>(apb + kn);
    a1 = *reinterpret_cast<const uint4*>(apb + kn + 8);
    b0 = *reinterpret_cast<const uint4*>(bpb + kn);
    b1 = *reinterpret_cast<const uint4*>(bpb + kn + 8);

    v8s af[4], bf[4];
    #pragma unroll
    for (int mt = 0; mt < 4; ++mt)
      af[mt] = *reinterpret_cast<const v8s*>(&As[(wm*64 + mt*16 + mi)*40 + quad*8]);
    #pragma unroll
    for (int nt = 0; nt < 4; ++nt)
      bf[nt] = *reinterpret_cast<const v8s*>(&Bs[(wn*64 + nt*16 + mi)*40 + quad*8]);
    #pragma unroll
    for (int mt = 0; mt < 4; ++mt)
      #pragma unroll
      for (int nt = 0; nt < 4; ++nt)
        acc[mt][nt] = __builtin_amdgcn_mfma_f32_16x16x32_bf16(af[mt], bf[nt], acc[mt][nt], 0, 0, 0);
    __syncthreads();
  }

  #pragma unroll
  for (int nt = 0; nt < 4; ++nt) {
    const int col = n0 + wn*64 + nt*16 + mi;
    const float bc = bias[col];
    #pragma unroll
    for (int mt = 0; mt < 4; ++mt) {
      #pragma unroll
      for (int r = 0; r < 4; ++r) {
        const int row = m0 + wm*64 + mt*16 + quad*4 + r;
        Cmat[(size_t)row * Nn + col] = f2bb(acc[mt][nt][r] + bc);
      }
    }
  }
}

// ---------------------------------------------------------------------------
// Generic fp32-input MFMA GEMM (mlp stage 1) (unchanged, passing).
// ---------------------------------------------------------------------------
template<int KK, int NN, bool TANH>
__global__ __launch_bounds__(256) void gemm_f32_mfma(const float* __restrict__ Amat,
                                                     const float* __restrict__ Bmat,
                                                     const float* __restrict__ bias,
                                                     u16* __restrict__ Cmat)
{
  __shared__ u16 As[128 * 40];
  __shared__ u16 Bs[128 * 40];
  const int t = threadIdx.x;
  const int m0 = blockIdx.x * 128, n0 = blockIdx.y * 128;
  const int wave = t >> 6, lane = t & 63;
  const int wm = wave >> 1, wn = wave & 1;
  const int mi = lane & 15, quad = lane >> 4;

  v4f acc[4][4];
  #pragma unroll
  for (int a = 0; a < 4; ++a)
    #pragma unroll
    for (int b = 0; b < 4; ++b) acc[a][b] = (v4f){0.f, 0.f, 0.f, 0.f};

  const int srow = t >> 1, scol = (t & 1) * 16;
  const float* apb = Amat + (size_t)(m0 + srow) * KK + scol;
  const float* bpb = Bmat + (size_t)(n0 + srow) * KK + scol;

  float av[16], bv[16];
  #pragma unroll
  for (int i = 0; i < 4; ++i) {
    *reinterpret_cast<float4*>(&av[i*4]) = *reinterpret_cast<const float4*>(apb + i*4);
    *reinterpret_cast<float4*>(&bv[i*4]) = *reinterpret_cast<const float4*>(bpb + i*4);
  }

  for (int kt = 0; kt < KK; kt += 32) {
    *reinterpret_cast<uint4*>(&As[srow*40 + scol])     = pack8(&av[0]);
    *reinterpret_cast<uint4*>(&As[srow*40 + scol + 8]) = pack8(&av[8]);
    *reinterpret_cast<uint4*>(&Bs[srow*40 + scol])     = pack8(&bv[0]);
    *reinterpret_cast<uint4*>(&Bs[srow*40 + scol + 8]) = pack8(&bv[8]);
    __syncthreads();

    const int kn = (kt + 32 < KK) ? kt + 32 : 0;
    #pragma unroll
    for (int i = 0; i < 4; ++i) {
      *reinterpret_cast<float4*>(&av[i*4]) = *reinterpret_cast<const float4*>(apb + kn + i*4);
      *reinterpret_cast<float4*>(&bv[i*4]) = *reinterpret_cast<const float4*>(bpb + kn + i*4);
    }

    v8s af[4], bf[4];
    #pragma unroll
    for (int mt = 0; mt < 4; ++mt)
      af[mt] = *reinterpret_cast<const v8s*>(&As[(wm*64 + mt*16 + mi)*40 + quad*8]);
    #pragma unroll
    for (int nt = 0; nt < 4; ++nt)
      bf[nt] = *reinterpret_cast<const v8s*>(&Bs[(wn*64 + nt*16 + mi)*40 + quad*8]);
    #pragma unroll
    for (int mt = 0; mt < 4; ++mt)
      #pragma unroll
      for (int nt = 0; nt < 4; ++nt)
        acc[mt][nt] = __builtin_amdgcn_mfma_f32_16x16x32_bf16(af[mt], bf[nt], acc[mt][nt], 0, 0, 0);
    __syncthreads();
  }

  #pragma unroll
  for (int nt = 0; nt < 4; ++nt) {
    const int col = n0 + wn*64 + nt*16 + mi;
    const float bc = bias[col];
    #pragma unroll
    for (int mt = 0; mt < 4; ++mt) {
      #pragma unroll
      for (int r = 0; r < 4; ++r) {
        const int row = m0 + wm*64 + mt*16 + quad*4 + r;
        float val = acc[mt][nt][r] + bc;
        if constexpr (TANH) val = tanhf(val);
        Cmat[(size_t)row * NN + col] = f2bb(val);
      }
    }
  }
}

// ---------------------------------------------------------------------------
// mlp stage 2 via MFMA (unchanged, passing)
// ---------------------------------------------------------------------------
__global__ __launch_bounds__(256) void mlp2_mfma(const u16* __restrict__ H,
                                                 const float* __restrict__ W2,
                                                 const float* __restrict__ b2,
                                                 float* __restrict__ outp)
{
  __shared__ u16 As[128 * 40];
  __shared__ u16 Bs[128 * 40];
  const int t = threadIdx.x;
  const int m0 = blockIdx.x * 128;
  const int wave = t >> 6, lane = t & 63;
  const int wm = wave >> 1, wn = wave & 1;
  const int mi = lane & 15, quad = lane >> 4;
  const int srow = t >> 1, scol = (t & 1) * 16;

  v4f acc[4][4];
  #pragma unroll
  for (int a = 0; a < 4; ++a)
    #pragma unroll
    for (int b = 0; b < 4; ++b) acc[a][b] = (v4f){0.f, 0.f, 0.f, 0.f};

  for (int kt = 0; kt < 256; kt += 32) {
    const u16* ap = H + (size_t)(m0 + srow) * 256 + kt + scol;
    *reinterpret_cast<uint4*>(&As[srow*40 + scol])     = *reinterpret_cast<const uint4*>(ap);
    *reinterpret_cast<uint4*>(&As[srow*40 + scol + 8]) = *reinterpret_cast<const uint4*>(ap + 8);
    const float* bp = W2 + (size_t)srow * 256 + kt + scol;
    float bv[16];
    #pragma unroll
    for (int i = 0; i < 4; ++i)
      *reinterpret_cast<float4*>(&bv[i*4]) = *reinterpret_cast<const float4*>(bp + i*4);
    *reinterpret_cast<uint4*>(&Bs[srow*40 + scol])     = pack8(&bv[0]);
    *reinterpret_cast<uint4*>(&Bs[srow*40 + scol + 8]) = pack8(&bv[8]);
    __syncthreads();

    v8s af[4], bf[4];
    #pragma unroll
    for (int mt = 0; mt < 4; ++mt)
      af[mt] = *reinterpret_cast<const v8s*>(&As[(wm*64 + mt*16 + mi)*40 + quad*8]);
    #pragma unroll
    for (int nt = 0; nt < 4; ++nt)
      bf[nt] = *reinterpret_cast<const v8s*>(&Bs[(wn*64 + nt*16 + mi)*40 + quad*8]);
    #pragma unroll
    for (int mt = 0; mt < 4; ++mt)
      #pragma unroll
      for (int nt = 0; nt < 4; ++nt)
        acc[mt][nt] = __builtin_amdgcn_mfma_f32_16x16x32_bf16(af[mt], bf[nt], acc[mt][nt], 0, 0, 0);
    __syncthreads();
  }

  #pragma unroll
  for (int nt = 0; nt < 4; ++nt) {
    const int col = wn*64 + nt*16 + mi;   // 0..127
    const float bc = b2[col];
    #pragma unroll
    for (int mt = 0; mt < 4; ++mt) {
      #pragma unroll
      for (int r = 0; r < 4; ++r) {
        const int row = m0 + wm*64 + mt*16 + quad*4 + r;
        const int bi = row / 3, s = row - bi * 3;
        outp[(size_t)s * (Bn*128) + (size_t)bi * 128 + col] = acc[mt][nt][r] + bc;
      }
    }
  }
}

// ---------------------------------------------------------------------------
// qkv via MFMA v2: A fragments loaded DIRECTLY from global (xt rows are
// 64-wide = exactly the fragment layout; each A element was read from LDS
// only once before, so staging was pure overhead). LDS = Bs only (9 KB).
// ---------------------------------------------------------------------------
__global__ __launch_bounds__(256) void qkv_mfma(const u16* __restrict__ xt, const float* __restrict__ Wqkv,
                                                u16* __restrict__ qh, u16* __restrict__ kh, u16* __restrict__ vb)
{
  __shared__ u16 Bs[64 * 72];
  const int t = threadIdx.x;
  const int m0 = blockIdx.x * 256;
  const int seg = blockIdx.y;
  const int wave = t >> 6, lane = t & 63;
  const int mi = lane & 15, quad = lane >> 4;

  for (int i = t; i < Cc*Cc; i += 256) {
    const int j = i >> 6, c = i & 63;
    Bs[j*72 + c] = f2bb(Wqkv[(size_t)(seg*64 + j)*64 + c]);
  }
  __syncthreads();

  v4f acc[4][4];
  #pragma unroll
  for (int a = 0; a < 4; ++a)
    #pragma unroll
    for (int b = 0; b < 4; ++b) acc[a][b] = (v4f){0.f, 0.f, 0.f, 0.f};

  #pragma unroll
  for (int ks = 0; ks < 2; ++ks) {
    v8s af[4], bf[4];
    #pragma unroll
    for (int mt = 0; mt < 4; ++mt)
      af[mt] = *reinterpret_cast<const v8s*>(xt + (size_t)(m0 + wave*64 + mt*16 + mi)*64 + ks*32 + quad*8);
    #pragma unroll
    for (int nt = 0; nt < 4; ++nt)
      bf[nt] = *reinterpret_cast<const v8s*>(&Bs[(nt*16 + mi)*72 + ks*32 + quad*8]);
    #pragma unroll
    for (int mt = 0; mt < 4; ++mt)
      #pragma unroll
      for (int nt = 0; nt < 4; ++nt)
        acc[mt][nt] = __builtin_amdgcn_mfma_f32_16x16x32_bf16(af[mt], bf[nt], acc[mt][nt], 0, 0, 0);
  }

  u16* hm = (seg == 0) ? qh : kh;
  #pragma unroll
  for (int nt = 0; nt < 4; ++nt) {
    const int col = nt*16 + mi;
    const int h = col >> 3, d = col & 7;
    #pragma unroll
    for (int mt = 0; mt < 4; ++mt) {
      #pragma unroll
      for (int r = 0; r < 4; ++r) {
        const int row = m0 + wave*64 + mt*16 + quad*4 + r;
        const u16 val = f2bb(acc[mt][nt][r]);
        if (seg < 2) {
          const int b = row / Nc, n = row - b * Nc;
          hm[((size_t)(b*NHc + h)*Nc + n)*8 + d] = val;
        } else {
          vb[(size_t)row * 64 + col] = val;
        }
      }
    }
  }
}

// ---------------------------------------------------------------------------
// position-bias precompute, transposed layouts (unchanged, passing)
// ---------------------------------------------------------------------------
__global__ __launch_bounds__(256) void bias_kernel(const float* __restrict__ an, const float* __restrict__ na,
                                                   const float* __restrict__ ah, const float* __restrict__ aw,
                                                   const float* __restrict__ ha, const float* __restrict__ wa,
                                                   float* __restrict__ pb, float* __restrict__ ab)
{
  const int total = NHc * Ac * Nc;   // 76832
  int idx = blockIdx.x * 256 + threadIdx.x;
  if (idx >= 2 * total) return;
  const bool isab = idx >= total;
  const int r = isab ? idx - total : idx;
  const int h = r / (Ac * Nc);
  const int r2 = r % (Ac * Nc);
  int a, n;
  if (isab) { n = r2 / Ac; a = r2 % Ac; } else { a = r2 / Nc; n = r2 % Nc; }
  const int y = n / WINc, x = n % WINc;
  float sy = fminf(fmaxf(0.5f * y - 0.25f, 0.f), 6.f);
  float sx = fminf(fmaxf(0.5f * x - 0.25f, 0.f), 6.f);
  const int y0 = (int)sy, x0 = (int)sx;
  const float wy = sy - y0, wx = sx - x0;
  const int y1 = (y0 + 1 < 6) ? y0 + 1 : 6;
  const int x1 = (x0 + 1 < 6) ? x0 + 1 : 6;
  const float* src = (isab ? na : an) + (h * Ac + a) * 49;
  const float v00 = src[y0*7 + x0], v01 = src[y0*7 + x1];
  const float v10 = src[y1*7 + x0], v11 = src[y1*7 + x1];
  const float bi = (1.f - wy) * ((1.f - wx) * v00 + wx * v01)
                 + wy * ((1.f - wx) * v10 + wx * v11);
  if (!isab) pb[((size_t)h*Nc + n)*Ac + a] = bi + ah[(h*Ac + a)*WINc + y] + aw[(h*Ac + a)*WINc + x];
  else       ab[((size_t)h*Ac + a)*Nc + n] = bi + ha[(h*WINc + y)*Ac + a] + wa[(h*WINc + x)*Ac + a];
}

// ---------------------------------------------------------------------------
// fused agent attention v6 (unchanged — measured best: 113 µs).
// ---------------------------------------------------------------------------
__global__ __launch_bounds__(256) void attn_kernel(const u16* __restrict__ qh, const u16* __restrict__ kh,
                                                   const u16* __restrict__ v,
                                                   const float* __restrict__ pb, const float* __restrict__ ab,
                                                   u16* __restrict__ o)
{
  __shared__ float sU[Nc*10];        // union: sQ (Nc*8) then sPart (Nc*9 used)
  __shared__ float sK[Nc*8], sV[Nc*8];
  __shared__ float sAg[Ac*8], sAV[Ac*8];
  const int bh = blockIdx.x;
  const int b = bh >> 3, h = bh & 7;
  const int t = threadIdx.x;
  const float scale = 0.3535533905932738f;

  float qreg[8];
  if (t < Nc) {
    const size_t base = ((size_t)bh * Nc + t) * 8;
    unpack8(*reinterpret_cast<const uint4*>(qh + base), qreg);
    #pragma unroll
    for (int d = 0; d < 8; ++d) sU[t*8 + d] = qreg[d];   // sQ view
    unpack8(*reinterpret_cast<const uint4*>(kh + base), &sK[t*8]);
    unpack8(*reinterpret_cast<const uint4*>(v + ((size_t)b*Nc + t)*64 + h*8), &sV[t*8]);
  }
  __syncthreads();

  for (int i = t; i < Ac*8; i += 256) {
    const int a = i >> 3, d = i & 7;
    const int ay = a / 7, ax = a % 7;
    const int n00 = (ay * 2) * WINc + ax * 2;
    sAg[i] = 0.25f * (sU[n00*8+d] + sU[(n00+1)*8+d] + sU[(n00+WINc)*8+d] + sU[(n00+WINc+1)*8+d]);
  }
  __syncthreads();   // sQ reads done; sU becomes sPart

  // stage 1: thread t<196 -> quarter qd, agent a; 2-way unrolled
  if (t < Nc) {
    const int qd = t / Ac, a = t - qd * Ac;
    const int nb = qd * Ac;
    v2f g2[4];
    #pragma unroll
    for (int d2 = 0; d2 < 4; ++d2) g2[d2] = *reinterpret_cast<const v2f*>(&sAg[a*8 + d2*2]);
    const float* pbr = pb + ((size_t)h*Nc + nb)*Ac + a;   // step Ac per j
    float l0 = 0.f, l1 = 0.f;
    v2f avA[4] = {}, avB[4] = {};
    for (int j = 0; j < 48; j += 2) {
      const v2f* k0 = reinterpret_cast<const v2f*>(&sK[(nb + j)*8]);
      const v2f* k1 = reinterpret_cast<const v2f*>(&sK[(nb + j + 1)*8]);
      v2f sa = (g2[0]*k0[0] + g2[1]*k0[1]) + (g2[2]*k0[2] + g2[3]*k0[3]);
      v2f sb = (g2[0]*k1[0] + g2[1]*k1[1]) + (g2[2]*k1[2] + g2[3]*k1[3]);
      const float e0 = __expf((sa.x + sa.y) * scale + pbr[j*Ac]);
      const float e1 = __expf((sb.x + sb.y) * scale + pbr[(j+1)*Ac]);
      l0 += e0; l1 += e1;
      const v2f* v0 = reinterpret_cast<const v2f*>(&sV[(nb + j)*8]);
      const v2f* v1 = reinterpret_cast<const v2f*>(&sV[(nb + j + 1)*8]);
      const v2f e02 = {e0, e0}, e12 = {e1, e1};
      #pragma unroll
      for (int d2 = 0; d2 < 4; ++d2) { avA[d2] += e02 * v0[d2]; avB[d2] += e12 * v1[d2]; }
    }
    { // tail j = 48
      const v2f* k0 = reinterpret_cast<const v2f*>(&sK[(nb + 48)*8]);
      v2f sa = (g2[0]*k0[0] + g2[1]*k0[1]) + (g2[2]*k0[2] + g2[3]*k0[3]);
      const float e0 = __expf((sa.x + sa.y) * scale + pbr[48*Ac]);
      l0 += e0;
      const v2f* v0 = reinterpret_cast<const v2f*>(&sV[(nb + 48)*8]);
      const v2f e02 = {e0, e0};
      #pragma unroll
      for (int d2 = 0; d2 < 4; ++d2) avA[d2] += e02 * v0[d2];
    }
    float* pp = &sU[t*9];            // sPart view
    pp[0] = l0 + l1;
    #pragma unroll
    for (int d2 = 0; d2 < 4; ++d2) {
      const v2f m = avA[d2] + avB[d2];
      pp[1+d2*2] = m.x; pp[2+d2*2] = m.y;
    }
  }
  __syncthreads();

  if (t < Ac) {
    float L = 0.f, av[8] = {};
    #pragma unroll
    for (int p = 0; p < 4; ++p) {
      const float* pp = &sU[(p*Ac + t)*9];
      L += pp[0];
      #pragma unroll
      for (int d = 0; d < 8; ++d) av[d] += pp[1+d];
    }
    const float inv = 1.f / L;
    #pragma unroll
    for (int d = 0; d < 8; ++d) sAV[t*8 + d] = av[d] * inv;
  }
  __syncthreads();

  // stage 2: thread = token n; 2-way unrolled over agents
  if (t < Nc) {
    v2f q2[4];
    #pragma unroll
    for (int d2 = 0; d2 < 4; ++d2) q2[d2] = (v2f){qreg[d2*2], qreg[d2*2+1]};
    const float* abr = ab + (size_t)h*Ac*Nc + t;          // step Nc per a
    float l0 = 0.f, l1 = 0.f;
    v2f oA[4] = {}, oB[4] = {};
    for (int a = 0; a < 48; a += 2) {
      const v2f* g0 = reinterpret_cast<const v2f*>(&sAg[a*8]);
      const v2f* g1 = reinterpret_cast<const v2f*>(&sAg[(a+1)*8]);
      v2f sa = (q2[0]*g0[0] + q2[1]*g0[1]) + (q2[2]*g0[2] + q2[3]*g0[3]);
      v2f sb = (q2[0]*g1[0] + q2[1]*g1[1]) + (q2[2]*g1[2] + q2[3]*g1[3]);
      const float e0 = __expf((sa.x + sa.y) * scale + abr[a*Nc]);
      const float e1 = __expf((sb.x + sb.y) * scale + abr[(a+1)*Nc]);
      l0 += e0; l1 += e1;
      const v2f* a0 = reinterpret_cast<const v2f*>(&sAV[a*8]);
      const v2f* a1 = reinterpret_cast<const v2f*>(&sAV[(a+1)*8]);
      const v2f e02 = {e0, e0}, e12 = {e1, e1};
      #pragma unroll
      for (int d2 = 0; d2 < 4; ++d2) { oA[d2] += e02 * a0[d2]; oB[d2] += e12 * a1[d2]; }
    }
    { // tail a = 48
      const v2f* g0 = reinterpret_cast<const v2f*>(&sAg[48*8]);
      v2f sa = (q2[0]*g0[0] + q2[1]*g0[1]) + (q2[2]*g0[2] + q2[3]*g0[3]);
      const float e0 = __expf((sa.x + sa.y) * scale + abr[48*Nc]);
      l0 += e0;
      const v2f* a0 = reinterpret_cast<const v2f*>(&sAV[48*8]);
      const v2f e02 = {e0, e0};
      #pragma unroll
      for (int d2 = 0; d2 < 4; ++d2) oA[d2] += e02 * a0[d2];
    }
    const float inv = 1.f / (l0 + l1);
    float o8[8];
    #pragma unroll
    for (int d2 = 0; d2 < 4; ++d2) {
      const v2f m = oA[d2] + oB[d2];
      o8[d2*2] = m.x * inv; o8[d2*2+1] = m.y * inv;
    }
    *reinterpret_cast<uint4*>(&o[((size_t)b*Nc + t)*64 + h*8]) = pack8(o8);
  }
}

// ---------------------------------------------------------------------------
// dwc 3x3 depthwise + residual v2: channel-PAIR processing (u32 loads/stores,
// halved loop iterations and index math).
// ---------------------------------------------------------------------------
__global__ __launch_bounds__(256) void dwc_kernel(const u16* __restrict__ o, const u16* __restrict__ v,
                                                  const float* __restrict__ dwc_w, const float* __restrict__ dwc_b,
                                                  u16* __restrict__ U)
{
  __shared__ u16 sV[Nc*Cc];
  const int b = blockIdx.x, t = threadIdx.x;

  const uint2* vsrc = reinterpret_cast<const uint2*>(v + (size_t)b * CNc);
  uint2* sV2 = reinterpret_cast<uint2*>(sV);
  for (int i = t; i < CNc/4; i += 256) sV2[i] = vsrc[i];
  __syncthreads();

  const u16* ob = o + (size_t)b * CNc;
  u16* ub = U + (size_t)b * CNc;
  for (int i = t; i < CNc/2; i += 256) {
    const int n = i >> 5, c2 = i & 31;       // c = 2*c2, 2*c2+1
    const int c = c2 * 2;
    const int y = n / WINc, x = n % WINc;
    const u32 resid = *reinterpret_cast<const u32*>(&ob[n*64 + c]);
    float acc0 = dwc_b[c]   + bflo(resid);
    float acc1 = dwc_b[c+1] + bfhi(resid);
    #pragma unroll
    for (int ky = 0; ky < 3; ++ky) {
      const int yy = y + ky - 1;
      if (yy < 0 || yy >= WINc) continue;
      #pragma unroll
      for (int kx = 0; kx < 3; ++kx) {
        const int xx = x + kx - 1;
        if (xx < 0 || xx >= WINc) continue;
        const u32 vv = *reinterpret_cast<const u32*>(&sV[(yy*WINc + xx)*Cc + c]);
        acc0 = fmaf(dwc_w[c*9 + ky*3 + kx],     bflo(vv), acc0);
        acc1 = fmaf(dwc_w[(c+1)*9 + ky*3 + kx], bfhi(vv), acc1);
      }
    }
    *reinterpret_cast<u32*>(&ub[n*64 + c]) = (u32)f2bb(acc0) | ((u32)f2bb(acc1) << 16);
  }
}

// ---------------------------------------------------------------------------
// proj GEMM via MFMA v2: A fragments direct from global (single-use staging
// removed). LDS = Bs only (9 KB) -> much higher occupancy.
// ---------------------------------------------------------------------------
__global__ __launch_bounds__(256) void proj_mfma(const u16* __restrict__ U,
                                                 const float* __restrict__ Wp,
                                                 const float* __restrict__ bp,
                                                 u16* __restrict__ oproj)
{
  __shared__ u16 Bs[64 * 72];
  const int t = threadIdx.x;
  const int m0 = blockIdx.x * 256;
  const int wave = t >> 6, lane = t & 63;
  const int mi = lane & 15, quad = lane >> 4;

  for (int i = t; i < Cc*Cc; i += 256) {
    const int j = i >> 6, c = i & 63;
    Bs[j*72 + c] = f2bb(Wp[i]);
  }
  __syncthreads();

  v4f acc[4][4];
  #pragma unroll
  for (int a = 0; a < 4; ++a)
    #pragma unroll
    for (int b = 0; b < 4; ++b) acc[a][b] = (v4f){0.f, 0.f, 0.f, 0.f};

  #pragma unroll
  for (int ks = 0; ks < 2; ++ks) {
    v8s af[4], bf[4];
    #pragma unroll
    for (int mt = 0; mt < 4; ++mt)
      af[mt] = *reinterpret_cast<const v8s*>(U + (size_t)(m0 + wave*64 + mt*16 + mi)*64 + ks*32 + quad*8);
    #pragma unroll
    for (int nt = 0; nt < 4; ++nt)
      bf[nt] = *reinterpret_cast<const v8s*>(&Bs[(nt*16 + mi)*72 + ks*32 + quad*8]);
    #pragma unroll
    for (int mt = 0; mt < 4; ++mt)
      #pragma unroll
      for (int nt = 0; nt < 4; ++nt)
        acc[mt][nt] = __builtin_amdgcn_mfma_f32_16x16x32_bf16(af[mt], bf[nt], acc[mt][nt], 0, 0, 0);
  }

  #pragma unroll
  for (int nt = 0; nt < 4; ++nt) {
    const int col = nt*16 + mi;
    const float bc = bp[col];
    #pragma unroll
    for (int mt = 0; mt < 4; ++mt) {
      #pragma unroll
      for (int r = 0; r < 4; ++r) {
        const int row = m0 + wave*64 + mt*16 + quad*4 + r;
        oproj[(size_t)row * 64 + col] = f2bb(acc[mt][nt][r] + bc);
      }
    }
  }
}

// ---------------------------------------------------------------------------
// adjacency GEMM via MFMA, split-K(8) v2: A fragments direct from global
// (single-use staging removed); B (bf16, pre-converted) stays in LDS.
// ---------------------------------------------------------------------------
__global__ __launch_bounds__(256) void gemm_adj_mfma(const u16* __restrict__ Amat,
                                                     const u16* __restrict__ BmatB,
                                                     float* __restrict__ part)
{
  constexpr int K = CNc, Kc = CNc/8;   // 1568 = 49*32
  __shared__ u16 Bs[64 * 40];
  const int t = threadIdx.x;
  const int m0 = blockIdx.y * 64, n0 = blockIdx.x * 64;
  const int kbeg = blockIdx.z * Kc;
  const int wave = t >> 6, lane = t & 63;
  const int mi = lane & 15, quad = lane >> 4;
  const int srow = t >> 2, sc8 = (t & 3) * 8;

  v4f acc[4];
  #pragma unroll
  for (int b = 0; b < 4; ++b) acc[b] = (v4f){0.f, 0.f, 0.f, 0.f};

  for (int kt = 0; kt < Kc; kt += 32) {
    {
      uint4 ub = *reinterpret_cast<const uint4*>(BmatB + (size_t)(n0 + srow) * K + kbeg + kt + sc8);
      *reinterpret_cast<uint4*>(&Bs[srow*40 + sc8]) = ub;
    }
    __syncthreads();
    v8s af = *reinterpret_cast<const v8s*>(Amat + (size_t)(m0 + wave*16 + mi) * K + kbeg + kt + quad*8);
    v8s bf[4];
    #pragma unroll
    for (int nt = 0; nt < 4; ++nt)
      bf[nt] = *reinterpret_cast<const v8s*>(&Bs[(nt*16 + mi)*40 + quad*8]);
    #pragma unroll
    for (int nt = 0; nt < 4; ++nt)
      acc[nt] = __builtin_amdgcn_mfma_f32_16x16x32_bf16(af, bf[nt], acc[nt], 0, 0, 0);
    __syncthreads();
  }

  const size_t zoff = (size_t)blockIdx.z * B3c * 256;
  #pragma unroll
  for (int nt = 0; nt < 4; ++nt) {
    const int col = n0 + nt*16 + mi;
    #pragma unroll
    for (int r = 0; r < 4; ++r) {
      const int row = m0 + wave*16 + quad*4 + r;
      part[zoff + (size_t)row * 256 + col] = acc[nt][r];
    }
  }
}

__global__ __launch_bounds__(256) void reduce_bias_kernel(const float* __restrict__ part,
                                                          const float* __restrict__ bias,
                                                          float* __restrict__ outp)
{
  const int idx = blockIdx.x * 256 + threadIdx.x;   // 768*256 exact
  const int n = idx & 255;
  float acc = bias[n];
  #pragma unroll
  for (int s = 0; s < 8; ++s) acc += part[(size_t)s * B3c * 256 + idx];
  outp[idx] = acc;                                  // fp32 output
}

// ---------------------------------------------------------------------------
extern "C" void kernel_launch(void* const* d_in, const int* in_sizes, int n_in,
                              void* d_out, int out_size, void* d_ws, size_t ws_size,
                              hipStream_t stream)
{
  auto in = [&](int i){ return reinterpret_cast<const float*>(d_in[i]); };
  const float *X = in(0), *We = in(1), *be = in(2), *Wq = in(3), *Wp = in(4), *bp = in(5),
              *dww = in(6), *dwb = in(7), *anb = in(8), *nab = in(9), *ahb = in(10), *awb = in(11),
              *hab = in(12), *wab = in(13), *Wadj = in(14), *badj = in(15),
              *W1 = in(16), *b1 = in(17), *W2 = in(18), *b2 = in(19);
  float* out = reinterpret_cast<float*>(d_out);
  char* w = reinterpret_cast<char*>(d_ws);

  const size_t TOK = (size_t)B3c * CNc;          // 9,633,792 elements
  u16* xt = reinterpret_cast<u16*>(w);            // slot0: xt -> o -> oproj
  u16* qh = reinterpret_cast<u16*>(w + TOK*2);    // slot1: We_bf[0:] -> q head-major -> U
  u16* kh = reinterpret_cast<u16*>(w + TOK*4);    // slot2: We_bf[..] -> k head-major -> part
  u16* vb = reinterpret_cast<u16*>(w + TOK*6);    // slot3: X_bf -> v token-major -> H
  float* pb = reinterpret_cast<float*>(w + TOK*8);
  float* ab = pb + NHc*Ac*Nc;
  u16* WadjB = reinterpret_cast<u16*>(ab + NHc*Ac*Nc);   // 6.4 MB, persistent
  u16* WeB = qh;                                  // 32.1 MB spans slot1+slot2 (38.5 MB)
  u16* XB  = vb;                                  // 2.0 MB in slot3
  u16* U = qh;                                    // alias: qh dead after attn
  float* part = reinterpret_cast<float*>(kh);     // alias: kh dead after attn
  u16* H = vb;                                    // alias: vb dead after dwc
  // total ws use: ~86.0 MB (<= 93.6 MB proven in R3)

  conv_bf16_kernel<<<dim3((WeN + XN + WadjN)/(256*8)), 256, 0, stream>>>(We, X, Wadj, WeB, XB, WadjB);
  gemm_embed_bf16<<<dim3(CNc/128, B3c/128), 256, 0, stream>>>(XB, WeB, be, xt);
  qkv_mfma<<<dim3((B3c*Nc)/256, 3), 256, 0, stream>>>(xt, Wq, qh, kh, vb);
  bias_kernel<<<dim3((2*NHc*Ac*Nc + 255)/256), 256, 0, stream>>>(anb, nab, ahb, awb, hab, wab, pb, ab);
  attn_kernel<<<dim3(B3c*NHc), 256, 0, stream>>>(qh, kh, vb, pb, ab, xt /*o*/);
  dwc_kernel<<<dim3(B3c), 256, 0, stream>>>(xt /*o*/, vb, dww, dwb, U);
  proj_mfma<<<dim3((B3c*Nc)/256), 256, 0, stream>>>(U, Wp, bp, xt /*oproj*/);
  gemm_adj_mfma<<<dim3(256/64, B3c/64, 8), 256, 0, stream>>>(xt /*oproj*/, WadjB, part);
  reduce_bias_kernel<<<dim3((B3c*256)/256), 256, 0, stream>>>(part, badj, out + 3*Bn*128);
  gemm_f32_mfma<Dd, 256, true><<<dim3(B3c/128, 2), 256, 0, stream>>>(X, W1, b1, H);
  mlp2_mfma<<<dim3(B3c/128), 256, 0, stream>>>(H, W2, b2, out);
}

// Round 16
// 548.776 us; speedup vs baseline: 1.0216x; 1.0216x over previous
//
#include <hip/hip_runtime.h>

using u16 = unsigned short;
using u32 = unsigned int;

constexpr int Bn   = 256;
constexpr int Dd   = 1280;
constexpr int Cc   = 64;
constexpr int WINc = 14;
constexpr int NHc  = 8;
constexpr int Ac   = 49;
constexpr int Nc   = WINc * WINc;   // 196
constexpr int HDc  = Cc / NHc;      // 8
constexpr int B3c  = 3 * Bn;        // 768
constexpr int CNc  = Cc * Nc;       // 12544

typedef __attribute__((ext_vector_type(8))) short v8s;   // 8 bf16 = 4 VGPRs
typedef __attribute__((ext_vector_type(4))) float v4f;
typedef __attribute__((ext_vector_type(2))) float v2f;   // packed fp32 (v_pk_*)

// bf16 helpers: inputs fp32, workspace intermediates bf16, OUTPUT fp32.
__device__ __forceinline__ float bflo(u32 u){ union{u32 x; float f;} c; c.x = u << 16; return c.f; }
__device__ __forceinline__ float bfhi(u32 u){ union{u32 x; float f;} c; c.x = u & 0xffff0000u; return c.f; }
__device__ __forceinline__ float bfs(u16 h){ union{u32 x; float f;} c; c.x = ((u32)h) << 16; return c.f; }
__device__ __forceinline__ u16 f2bb(float f){
  u32 u = __float_as_uint(f);
  u32 r = (u + 0x7fffu + ((u >> 16) & 1u)) >> 16;
  return (u16)r;
}
__device__ __forceinline__ void unpack8(uint4 u, float* dst){
  dst[0]=bflo(u.x); dst[1]=bfhi(u.x); dst[2]=bflo(u.y); dst[3]=bfhi(u.y);
  dst[4]=bflo(u.z); dst[5]=bfhi(u.z); dst[6]=bflo(u.w); dst[7]=bfhi(u.w);
}
__device__ __forceinline__ uint4 pack8(const float* s){
  uint4 r;
  r.x = (u32)f2bb(s[0]) | ((u32)f2bb(s[1]) << 16);
  r.y = (u32)f2bb(s[2]) | ((u32)f2bb(s[3]) << 16);
  r.z = (u32)f2bb(s[4]) | ((u32)f2bb(s[5]) << 16);
  r.w = (u32)f2bb(s[6]) | ((u32)f2bb(s[7]) << 16);
  return r;
}

// ---------------------------------------------------------------------------
// One-time fp32->bf16 conversion of W_embed, X, W_adj (unchanged, passing).
// ---------------------------------------------------------------------------
constexpr int WeN   = 12544 * 1280;   // 16,056,320
constexpr int XN    = 768 * 1280;     //    983,040
constexpr int WadjN = 256 * CNc;      //  3,211,264
__global__ __launch_bounds__(256) void conv_bf16_kernel(const float* __restrict__ We,
                                                        const float* __restrict__ X,
                                                        const float* __restrict__ Wadj,
                                                        u16* __restrict__ WeB,
                                                        u16* __restrict__ XB,
                                                        u16* __restrict__ WadjB)
{
  const size_t idx = ((size_t)blockIdx.x * 256 + threadIdx.x) * 8;
  const float* src; u16* dst;
  if (idx < (size_t)WeN)            { src = We + idx;               dst = WeB + idx; }
  else if (idx < (size_t)WeN + XN)  { src = X + (idx - WeN);        dst = XB + (idx - WeN); }
  else                              { src = Wadj + (idx - WeN - XN); dst = WadjB + (idx - WeN - XN); }
  float v[8];
  *reinterpret_cast<float4*>(&v[0]) = *reinterpret_cast<const float4*>(src);
  *reinterpret_cast<float4*>(&v[4]) = *reinterpret_cast<const float4*>(src + 4);
  *reinterpret_cast<uint4*>(dst) = pack8(v);
}

// ---------------------------------------------------------------------------
// embed GEMM, all-bf16 inputs (unchanged, passing).
// ---------------------------------------------------------------------------
__global__ __launch_bounds__(256) void gemm_embed_bf16(const u16* __restrict__ Amat,
                                                       const u16* __restrict__ Bmat,
                                                       const float* __restrict__ bias,
                                                       u16* __restrict__ Cmat)
{
  constexpr int K = Dd, Nn = CNc;
  __shared__ u16 As[128 * 40];
  __shared__ u16 Bs[128 * 40];
  const int t = threadIdx.x;
  const int n0 = blockIdx.x * 128, m0 = blockIdx.y * 128;   // n fastest
  const int wave = t >> 6, lane = t & 63;
  const int wm = wave >> 1, wn = wave & 1;
  const int mi = lane & 15, quad = lane >> 4;

  v4f acc[4][4];
  #pragma unroll
  for (int a = 0; a < 4; ++a)
    #pragma unroll
    for (int b = 0; b < 4; ++b) acc[a][b] = (v4f){0.f, 0.f, 0.f, 0.f};

  const int srow = t >> 1, scol = (t & 1) * 16;
  const u16* apb = Amat + (size_t)(m0 + srow) * K + scol;
  const u16* bpb = Bmat + (size_t)(n0 + srow) * K + scol;

  uint4 a0 = *reinterpret_cast<const uint4*>(apb);
  uint4 a1 = *reinterpret_cast<const uint4*>(apb + 8);
  uint4 b0 = *reinterpret_cast<const uint4*>(bpb);
  uint4 b1 = *reinterpret_cast<const uint4*>(bpb + 8);

  for (int kt = 0; kt < K; kt += 32) {
    *reinterpret_cast<uint4*>(&As[srow*40 + scol])     = a0;
    *reinterpret_cast<uint4*>(&As[srow*40 + scol + 8]) = a1;
    *reinterpret_cast<uint4*>(&Bs[srow*40 + scol])     = b0;
    *reinterpret_cast<uint4*>(&Bs[srow*40 + scol + 8]) = b1;
    __syncthreads();

    const int kn = (kt + 32 < K) ? kt + 32 : 0;   // clamped prefetch
    a0 = *reinterpret_cast<const uint4*>(apb + kn);
    a1 = *reinterpret_cast<const uint4*>(apb + kn + 8);
    b0 = *reinterpret_cast<const uint4*>(bpb + kn);
    b1 = *reinterpret_cast<const uint4*>(bpb + kn + 8);

    v8s af[4], bf[4];
    #pragma unroll
    for (int mt = 0; mt < 4; ++mt)
      af[mt] = *reinterpret_cast<const v8s*>(&As[(wm*64 + mt*16 + mi)*40 + quad*8]);
    #pragma unroll
    for (int nt = 0; nt < 4; ++nt)
      bf[nt] = *reinterpret_cast<const v8s*>(&Bs[(wn*64 + nt*16 + mi)*40 + quad*8]);
    #pragma unroll
    for (int mt = 0; mt < 4; ++mt)
      #pragma unroll
      for (int nt = 0; nt < 4; ++nt)
        acc[mt][nt] = __builtin_amdgcn_mfma_f32_16x16x32_bf16(af[mt], bf[nt], acc[mt][nt], 0, 0, 0);
    __syncthreads();
  }

  #pragma unroll
  for (int nt = 0; nt < 4; ++nt) {
    const int col = n0 + wn*64 + nt*16 + mi;
    const float bc = bias[col];
    #pragma unroll
    for (int mt = 0; mt < 4; ++mt) {
      #pragma unroll
      for (int r = 0; r < 4; ++r) {
        const int row = m0 + wm*64 + mt*16 + quad*4 + r;
        Cmat[(size_t)row * Nn + col] = f2bb(acc[mt][nt][r] + bc);
      }
    }
  }
}

// ---------------------------------------------------------------------------
// Generic fp32-input MFMA GEMM (mlp stage 1) (unchanged, passing).
// ---------------------------------------------------------------------------
template<int KK, int NN, bool TANH>
__global__ __launch_bounds__(256) void gemm_f32_mfma(const float* __restrict__ Amat,
                                                     const float* __restrict__ Bmat,
                                                     const float* __restrict__ bias,
                                                     u16* __restrict__ Cmat)
{
  __shared__ u16 As[128 * 40];
  __shared__ u16 Bs[128 * 40];
  const int t = threadIdx.x;
  const int m0 = blockIdx.x * 128, n0 = blockIdx.y * 128;
  const int wave = t >> 6, lane = t & 63;
  const int wm = wave >> 1, wn = wave & 1;
  const int mi = lane & 15, quad = lane >> 4;

  v4f acc[4][4];
  #pragma unroll
  for (int a = 0; a < 4; ++a)
    #pragma unroll
    for (int b = 0; b < 4; ++b) acc[a][b] = (v4f){0.f, 0.f, 0.f, 0.f};

  const int srow = t >> 1, scol = (t & 1) * 16;
  const float* apb = Amat + (size_t)(m0 + srow) * KK + scol;
  const float* bpb = Bmat + (size_t)(n0 + srow) * KK + scol;

  float av[16], bv[16];
  #pragma unroll
  for (int i = 0; i < 4; ++i) {
    *reinterpret_cast<float4*>(&av[i*4]) = *reinterpret_cast<const float4*>(apb + i*4);
    *reinterpret_cast<float4*>(&bv[i*4]) = *reinterpret_cast<const float4*>(bpb + i*4);
  }

  for (int kt = 0; kt < KK; kt += 32) {
    *reinterpret_cast<uint4*>(&As[srow*40 + scol])     = pack8(&av[0]);
    *reinterpret_cast<uint4*>(&As[srow*40 + scol + 8]) = pack8(&av[8]);
    *reinterpret_cast<uint4*>(&Bs[srow*40 + scol])     = pack8(&bv[0]);
    *reinterpret_cast<uint4*>(&Bs[srow*40 + scol + 8]) = pack8(&bv[8]);
    __syncthreads();

    const int kn = (kt + 32 < KK) ? kt + 32 : 0;
    #pragma unroll
    for (int i = 0; i < 4; ++i) {
      *reinterpret_cast<float4*>(&av[i*4]) = *reinterpret_cast<const float4*>(apb + kn + i*4);
      *reinterpret_cast<float4*>(&bv[i*4]) = *reinterpret_cast<const float4*>(bpb + kn + i*4);
    }

    v8s af[4], bf[4];
    #pragma unroll
    for (int mt = 0; mt < 4; ++mt)
      af[mt] = *reinterpret_cast<const v8s*>(&As[(wm*64 + mt*16 + mi)*40 + quad*8]);
    #pragma unroll
    for (int nt = 0; nt < 4; ++nt)
      bf[nt] = *reinterpret_cast<const v8s*>(&Bs[(wn*64 + nt*16 + mi)*40 + quad*8]);
    #pragma unroll
    for (int mt = 0; mt < 4; ++mt)
      #pragma unroll
      for (int nt = 0; nt < 4; ++nt)
        acc[mt][nt] = __builtin_amdgcn_mfma_f32_16x16x32_bf16(af[mt], bf[nt], acc[mt][nt], 0, 0, 0);
    __syncthreads();
  }

  #pragma unroll
  for (int nt = 0; nt < 4; ++nt) {
    const int col = n0 + wn*64 + nt*16 + mi;
    const float bc = bias[col];
    #pragma unroll
    for (int mt = 0; mt < 4; ++mt) {
      #pragma unroll
      for (int r = 0; r < 4; ++r) {
        const int row = m0 + wm*64 + mt*16 + quad*4 + r;
        float val = acc[mt][nt][r] + bc;
        if constexpr (TANH) val = tanhf(val);
        Cmat[(size_t)row * NN + col] = f2bb(val);
      }
    }
  }
}

// ---------------------------------------------------------------------------
// mlp stage 2 via MFMA (unchanged, passing)
// ---------------------------------------------------------------------------
__global__ __launch_bounds__(256) void mlp2_mfma(const u16* __restrict__ H,
                                                 const float* __restrict__ W2,
                                                 const float* __restrict__ b2,
                                                 float* __restrict__ outp)
{
  __shared__ u16 As[128 * 40];
  __shared__ u16 Bs[128 * 40];
  const int t = threadIdx.x;
  const int m0 = blockIdx.x * 128;
  const int wave = t >> 6, lane = t & 63;
  const int wm = wave >> 1, wn = wave & 1;
  const int mi = lane & 15, quad = lane >> 4;
  const int srow = t >> 1, scol = (t & 1) * 16;

  v4f acc[4][4];
  #pragma unroll
  for (int a = 0; a < 4; ++a)
    #pragma unroll
    for (int b = 0; b < 4; ++b) acc[a][b] = (v4f){0.f, 0.f, 0.f, 0.f};

  for (int kt = 0; kt < 256; kt += 32) {
    const u16* ap = H + (size_t)(m0 + srow) * 256 + kt + scol;
    *reinterpret_cast<uint4*>(&As[srow*40 + scol])     = *reinterpret_cast<const uint4*>(ap);
    *reinterpret_cast<uint4*>(&As[srow*40 + scol + 8]) = *reinterpret_cast<const uint4*>(ap + 8);
    const float* bp = W2 + (size_t)srow * 256 + kt + scol;
    float bv[16];
    #pragma unroll
    for (int i = 0; i < 4; ++i)
      *reinterpret_cast<float4*>(&bv[i*4]) = *reinterpret_cast<const float4*>(bp + i*4);
    *reinterpret_cast<uint4*>(&Bs[srow*40 + scol])     = pack8(&bv[0]);
    *reinterpret_cast<uint4*>(&Bs[srow*40 + scol + 8]) = pack8(&bv[8]);
    __syncthreads();

    v8s af[4], bf[4];
    #pragma unroll
    for (int mt = 0; mt < 4; ++mt)
      af[mt] = *reinterpret_cast<const v8s*>(&As[(wm*64 + mt*16 + mi)*40 + quad*8]);
    #pragma unroll
    for (int nt = 0; nt < 4; ++nt)
      bf[nt] = *reinterpret_cast<const v8s*>(&Bs[(wn*64 + nt*16 + mi)*40 + quad*8]);
    #pragma unroll
    for (int mt = 0; mt < 4; ++mt)
      #pragma unroll
      for (int nt = 0; nt < 4; ++nt)
        acc[mt][nt] = __builtin_amdgcn_mfma_f32_16x16x32_bf16(af[mt], bf[nt], acc[mt][nt], 0, 0, 0);
    __syncthreads();
  }

  #pragma unroll
  for (int nt = 0; nt < 4; ++nt) {
    const int col = wn*64 + nt*16 + mi;   // 0..127
    const float bc = b2[col];
    #pragma unroll
    for (int mt = 0; mt < 4; ++mt) {
      #pragma unroll
      for (int r = 0; r < 4; ++r) {
        const int row = m0 + wm*64 + mt*16 + quad*4 + r;
        const int bi = row / 3, s = row - bi * 3;
        outp[(size_t)s * (Bn*128) + (size_t)bi * 128 + col] = acc[mt][nt][r] + bc;
      }
    }
  }
}

// ---------------------------------------------------------------------------
// qkv via MFMA (R14 version: LDS-staged A — measured best)
// ---------------------------------------------------------------------------
__global__ __launch_bounds__(256) void qkv_mfma(const u16* __restrict__ xt, const float* __restrict__ Wqkv,
                                                u16* __restrict__ qh, u16* __restrict__ kh, u16* __restrict__ vb)
{
  __shared__ u16 As[256 * 72];
  __shared__ u16 Bs[64 * 72];
  const int t = threadIdx.x;
  const int m0 = blockIdx.x * 256;
  const int seg = blockIdx.y;
  const int wave = t >> 6, lane = t & 63;
  const int mi = lane & 15, quad = lane >> 4;

  for (int i = t; i < Cc*Cc; i += 256) {
    const int j = i >> 6, c = i & 63;
    Bs[j*72 + c] = f2bb(Wqkv[(size_t)(seg*64 + j)*64 + c]);
  }
  {
    const int ar = t >> 2, ac = (t & 3) * 16;
    #pragma unroll
    for (int rb = 0; rb < 4; ++rb) {
      const int row = rb*64 + ar;
      const uint4* src = reinterpret_cast<const uint4*>(xt + ((size_t)(m0 + row))*64 + ac);
      *reinterpret_cast<uint4*>(&As[row*72 + ac])     = src[0];
      *reinterpret_cast<uint4*>(&As[row*72 + ac + 8]) = src[1];
    }
  }
  __syncthreads();

  v4f acc[4][4];
  #pragma unroll
  for (int a = 0; a < 4; ++a)
    #pragma unroll
    for (int b = 0; b < 4; ++b) acc[a][b] = (v4f){0.f, 0.f, 0.f, 0.f};

  #pragma unroll
  for (int ks = 0; ks < 2; ++ks) {
    v8s af[4], bf[4];
    #pragma unroll
    for (int mt = 0; mt < 4; ++mt)
      af[mt] = *reinterpret_cast<const v8s*>(&As[(wave*64 + mt*16 + mi)*72 + ks*32 + quad*8]);
    #pragma unroll
    for (int nt = 0; nt < 4; ++nt)
      bf[nt] = *reinterpret_cast<const v8s*>(&Bs[(nt*16 + mi)*72 + ks*32 + quad*8]);
    #pragma unroll
    for (int mt = 0; mt < 4; ++mt)
      #pragma unroll
      for (int nt = 0; nt < 4; ++nt)
        acc[mt][nt] = __builtin_amdgcn_mfma_f32_16x16x32_bf16(af[mt], bf[nt], acc[mt][nt], 0, 0, 0);
  }

  u16* hm = (seg == 0) ? qh : kh;
  #pragma unroll
  for (int nt = 0; nt < 4; ++nt) {
    const int col = nt*16 + mi;
    const int h = col >> 3, d = col & 7;
    #pragma unroll
    for (int mt = 0; mt < 4; ++mt) {
      #pragma unroll
      for (int r = 0; r < 4; ++r) {
        const int row = m0 + wave*64 + mt*16 + quad*4 + r;
        const u16 val = f2bb(acc[mt][nt][r]);
        if (seg < 2) {
          const int b = row / Nc, n = row - b * Nc;
          hm[((size_t)(b*NHc + h)*Nc + n)*8 + d] = val;
        } else {
          vb[(size_t)row * 64 + col] = val;
        }
      }
    }
  }
}

// ---------------------------------------------------------------------------
// position-bias precompute, transposed layouts (unchanged, passing)
// ---------------------------------------------------------------------------
__global__ __launch_bounds__(256) void bias_kernel(const float* __restrict__ an, const float* __restrict__ na,
                                                   const float* __restrict__ ah, const float* __restrict__ aw,
                                                   const float* __restrict__ ha, const float* __restrict__ wa,
                                                   float* __restrict__ pb, float* __restrict__ ab)
{
  const int total = NHc * Ac * Nc;   // 76832
  int idx = blockIdx.x * 256 + threadIdx.x;
  if (idx >= 2 * total) return;
  const bool isab = idx >= total;
  const int r = isab ? idx - total : idx;
  const int h = r / (Ac * Nc);
  const int r2 = r % (Ac * Nc);
  int a, n;
  if (isab) { n = r2 / Ac; a = r2 % Ac; } else { a = r2 / Nc; n = r2 % Nc; }
  const int y = n / WINc, x = n % WINc;
  float sy = fminf(fmaxf(0.5f * y - 0.25f, 0.f), 6.f);
  float sx = fminf(fmaxf(0.5f * x - 0.25f, 0.f), 6.f);
  const int y0 = (int)sy, x0 = (int)sx;
  const float wy = sy - y0, wx = sx - x0;
  const int y1 = (y0 + 1 < 6) ? y0 + 1 : 6;
  const int x1 = (x0 + 1 < 6) ? x0 + 1 : 6;
  const float* src = (isab ? na : an) + (h * Ac + a) * 49;
  const float v00 = src[y0*7 + x0], v01 = src[y0*7 + x1];
  const float v10 = src[y1*7 + x0], v11 = src[y1*7 + x1];
  const float bi = (1.f - wy) * ((1.f - wx) * v00 + wx * v01)
                 + wy * ((1.f - wx) * v10 + wx * v11);
  if (!isab) pb[((size_t)h*Nc + n)*Ac + a] = bi + ah[(h*Ac + a)*WINc + y] + aw[(h*Ac + a)*WINc + x];
  else       ab[((size_t)h*Ac + a)*Nc + n] = bi + ha[(h*WINc + y)*Ac + a] + wa[(h*WINc + x)*Ac + a];
}

// ---------------------------------------------------------------------------
// fused agent attention v6 (unchanged — measured best: 112 µs).
// ---------------------------------------------------------------------------
__global__ __launch_bounds__(256) void attn_kernel(const u16* __restrict__ qh, const u16* __restrict__ kh,
                                                   const u16* __restrict__ v,
                                                   const float* __restrict__ pb, const float* __restrict__ ab,
                                                   u16* __restrict__ o)
{
  __shared__ float sU[Nc*10];        // union: sQ (Nc*8) then sPart (Nc*9 used)
  __shared__ float sK[Nc*8], sV[Nc*8];
  __shared__ float sAg[Ac*8], sAV[Ac*8];
  const int bh = blockIdx.x;
  const int b = bh >> 3, h = bh & 7;
  const int t = threadIdx.x;
  const float scale = 0.3535533905932738f;

  float qreg[8];
  if (t < Nc) {
    const size_t base = ((size_t)bh * Nc + t) * 8;
    unpack8(*reinterpret_cast<const uint4*>(qh + base), qreg);
    #pragma unroll
    for (int d = 0; d < 8; ++d) sU[t*8 + d] = qreg[d];   // sQ view
    unpack8(*reinterpret_cast<const uint4*>(kh + base), &sK[t*8]);
    unpack8(*reinterpret_cast<const uint4*>(v + ((size_t)b*Nc + t)*64 + h*8), &sV[t*8]);
  }
  __syncthreads();

  for (int i = t; i < Ac*8; i += 256) {
    const int a = i >> 3, d = i & 7;
    const int ay = a / 7, ax = a % 7;
    const int n00 = (ay * 2) * WINc + ax * 2;
    sAg[i] = 0.25f * (sU[n00*8+d] + sU[(n00+1)*8+d] + sU[(n00+WINc)*8+d] + sU[(n00+WINc+1)*8+d]);
  }
  __syncthreads();   // sQ reads done; sU becomes sPart

  // stage 1: thread t<196 -> quarter qd, agent a; 2-way unrolled
  if (t < Nc) {
    const int qd = t / Ac, a = t - qd * Ac;
    const int nb = qd * Ac;
    v2f g2[4];
    #pragma unroll
    for (int d2 = 0; d2 < 4; ++d2) g2[d2] = *reinterpret_cast<const v2f*>(&sAg[a*8 + d2*2]);
    const float* pbr = pb + ((size_t)h*Nc + nb)*Ac + a;   // step Ac per j
    float l0 = 0.f, l1 = 0.f;
    v2f avA[4] = {}, avB[4] = {};
    for (int j = 0; j < 48; j += 2) {
      const v2f* k0 = reinterpret_cast<const v2f*>(&sK[(nb + j)*8]);
      const v2f* k1 = reinterpret_cast<const v2f*>(&sK[(nb + j + 1)*8]);
      v2f sa = (g2[0]*k0[0] + g2[1]*k0[1]) + (g2[2]*k0[2] + g2[3]*k0[3]);
      v2f sb = (g2[0]*k1[0] + g2[1]*k1[1]) + (g2[2]*k1[2] + g2[3]*k1[3]);
      const float e0 = __expf((sa.x + sa.y) * scale + pbr[j*Ac]);
      const float e1 = __expf((sb.x + sb.y) * scale + pbr[(j+1)*Ac]);
      l0 += e0; l1 += e1;
      const v2f* v0 = reinterpret_cast<const v2f*>(&sV[(nb + j)*8]);
      const v2f* v1 = reinterpret_cast<const v2f*>(&sV[(nb + j + 1)*8]);
      const v2f e02 = {e0, e0}, e12 = {e1, e1};
      #pragma unroll
      for (int d2 = 0; d2 < 4; ++d2) { avA[d2] += e02 * v0[d2]; avB[d2] += e12 * v1[d2]; }
    }
    { // tail j = 48
      const v2f* k0 = reinterpret_cast<const v2f*>(&sK[(nb + 48)*8]);
      v2f sa = (g2[0]*k0[0] + g2[1]*k0[1]) + (g2[2]*k0[2] + g2[3]*k0[3]);
      const float e0 = __expf((sa.x + sa.y) * scale + pbr[48*Ac]);
      l0 += e0;
      const v2f* v0 = reinterpret_cast<const v2f*>(&sV[(nb + 48)*8]);
      const v2f e02 = {e0, e0};
      #pragma unroll
      for (int d2 = 0; d2 < 4; ++d2) avA[d2] += e02 * v0[d2];
    }
    float* pp = &sU[t*9];            // sPart view
    pp[0] = l0 + l1;
    #pragma unroll
    for (int d2 = 0; d2 < 4; ++d2) {
      const v2f m = avA[d2] + avB[d2];
      pp[1+d2*2] = m.x; pp[2+d2*2] = m.y;
    }
  }
  __syncthreads();

  if (t < Ac) {
    float L = 0.f, av[8] = {};
    #pragma unroll
    for (int p = 0; p < 4; ++p) {
      const float* pp = &sU[(p*Ac + t)*9];
      L += pp[0];
      #pragma unroll
      for (int d = 0; d < 8; ++d) av[d] += pp[1+d];
    }
    const float inv = 1.f / L;
    #pragma unroll
    for (int d = 0; d < 8; ++d) sAV[t*8 + d] = av[d] * inv;
  }
  __syncthreads();

  // stage 2: thread = token n; 2-way unrolled over agents
  if (t < Nc) {
    v2f q2[4];
    #pragma unroll
    for (int d2 = 0; d2 < 4; ++d2) q2[d2] = (v2f){qreg[d2*2], qreg[d2*2+1]};
    const float* abr = ab + (size_t)h*Ac*Nc + t;          // step Nc per a
    float l0 = 0.f, l1 = 0.f;
    v2f oA[4] = {}, oB[4] = {};
    for (int a = 0; a < 48; a += 2) {
      const v2f* g0 = reinterpret_cast<const v2f*>(&sAg[a*8]);
      const v2f* g1 = reinterpret_cast<const v2f*>(&sAg[(a+1)*8]);
      v2f sa = (q2[0]*g0[0] + q2[1]*g0[1]) + (q2[2]*g0[2] + q2[3]*g0[3]);
      v2f sb = (q2[0]*g1[0] + q2[1]*g1[1]) + (q2[2]*g1[2] + q2[3]*g1[3]);
      const float e0 = __expf((sa.x + sa.y) * scale + abr[a*Nc]);
      const float e1 = __expf((sb.x + sb.y) * scale + abr[(a+1)*Nc]);
      l0 += e0; l1 += e1;
      const v2f* a0 = reinterpret_cast<const v2f*>(&sAV[a*8]);
      const v2f* a1 = reinterpret_cast<const v2f*>(&sAV[(a+1)*8]);
      const v2f e02 = {e0, e0}, e12 = {e1, e1};
      #pragma unroll
      for (int d2 = 0; d2 < 4; ++d2) { oA[d2] += e02 * a0[d2]; oB[d2] += e12 * a1[d2]; }
    }
    { // tail a = 48
      const v2f* g0 = reinterpret_cast<const v2f*>(&sAg[48*8]);
      v2f sa = (q2[0]*g0[0] + q2[1]*g0[1]) + (q2[2]*g0[2] + q2[3]*g0[3]);
      const float e0 = __expf((sa.x + sa.y) * scale + abr[48*Nc]);
      l0 += e0;
      const v2f* a0 = reinterpret_cast<const v2f*>(&sAV[48*8]);
      const v2f e02 = {e0, e0};
      #pragma unroll
      for (int d2 = 0; d2 < 4; ++d2) oA[d2] += e02 * a0[d2];
    }
    const float inv = 1.f / (l0 + l1);
    float o8[8];
    #pragma unroll
    for (int d2 = 0; d2 < 4; ++d2) {
      const v2f m = oA[d2] + oB[d2];
      o8[d2*2] = m.x * inv; o8[d2*2+1] = m.y * inv;
    }
    *reinterpret_cast<uint4*>(&o[((size_t)b*Nc + t)*64 + h*8]) = pack8(o8);
  }
}

// ---------------------------------------------------------------------------
// dwc 3x3 depthwise + residual (R14 version — measured best)
// ---------------------------------------------------------------------------
__global__ __launch_bounds__(256) void dwc_kernel(const u16* __restrict__ o, const u16* __restrict__ v,
                                                  const float* __restrict__ dwc_w, const float* __restrict__ dwc_b,
                                                  u16* __restrict__ U)
{
  __shared__ u16 sV[Nc*Cc];
  const int b = blockIdx.x, t = threadIdx.x;

  const uint2* vsrc = reinterpret_cast<const uint2*>(v + (size_t)b * CNc);
  uint2* sV2 = reinterpret_cast<uint2*>(sV);
  for (int i = t; i < CNc/4; i += 256) sV2[i] = vsrc[i];
  __syncthreads();

  const u16* ob = o + (size_t)b * CNc;
  u16* ub = U + (size_t)b * CNc;
  for (int i = t; i < CNc; i += 256) {
    const int n = i >> 6, c = i & 63;
    const int y = n / WINc, x = n % WINc;
    float acc = dwc_b[c] + bfs(ob[i]);
    #pragma unroll
    for (int ky = 0; ky < 3; ++ky) {
      const int yy = y + ky - 1;
      if (yy < 0 || yy >= WINc) continue;
      #pragma unroll
      for (int kx = 0; kx < 3; ++kx) {
        const int xx = x + kx - 1;
        if (xx < 0 || xx >= WINc) continue;
        acc = fmaf(dwc_w[c*9 + ky*3 + kx], bfs(sV[(yy*WINc + xx)*Cc + c]), acc);
      }
    }
    ub[i] = f2bb(acc);
  }
}

// ---------------------------------------------------------------------------
// proj GEMM via MFMA (R14 version: LDS-staged A — measured best)
// ---------------------------------------------------------------------------
__global__ __launch_bounds__(256) void proj_mfma(const u16* __restrict__ U,
                                                 const float* __restrict__ Wp,
                                                 const float* __restrict__ bp,
                                                 u16* __restrict__ oproj)
{
  __shared__ u16 As[256 * 72];
  __shared__ u16 Bs[64 * 72];
  const int t = threadIdx.x;
  const int m0 = blockIdx.x * 256;
  const int wave = t >> 6, lane = t & 63;
  const int mi = lane & 15, quad = lane >> 4;

  for (int i = t; i < Cc*Cc; i += 256) {
    const int j = i >> 6, c = i & 63;
    Bs[j*72 + c] = f2bb(Wp[i]);
  }
  {
    const int ar = t >> 2, ac = (t & 3) * 16;
    #pragma unroll
    for (int rb = 0; rb < 4; ++rb) {
      const int row = rb*64 + ar;
      const uint4* src = reinterpret_cast<const uint4*>(U + ((size_t)(m0 + row))*64 + ac);
      *reinterpret_cast<uint4*>(&As[row*72 + ac])     = src[0];
      *reinterpret_cast<uint4*>(&As[row*72 + ac + 8]) = src[1];
    }
  }
  __syncthreads();

  v4f acc[4][4];
  #pragma unroll
  for (int a = 0; a < 4; ++a)
    #pragma unroll
    for (int b = 0; b < 4; ++b) acc[a][b] = (v4f){0.f, 0.f, 0.f, 0.f};

  #pragma unroll
  for (int ks = 0; ks < 2; ++ks) {
    v8s af[4], bf[4];
    #pragma unroll
    for (int mt = 0; mt < 4; ++mt)
      af[mt] = *reinterpret_cast<const v8s*>(&As[(wave*64 + mt*16 + mi)*72 + ks*32 + quad*8]);
    #pragma unroll
    for (int nt = 0; nt < 4; ++nt)
      bf[nt] = *reinterpret_cast<const v8s*>(&Bs[(nt*16 + mi)*72 + ks*32 + quad*8]);
    #pragma unroll
    for (int mt = 0; mt < 4; ++mt)
      #pragma unroll
      for (int nt = 0; nt < 4; ++nt)
        acc[mt][nt] = __builtin_amdgcn_mfma_f32_16x16x32_bf16(af[mt], bf[nt], acc[mt][nt], 0, 0, 0);
  }

  #pragma unroll
  for (int nt = 0; nt < 4; ++nt) {
    const int col = nt*16 + mi;
    const float bc = bp[col];
    #pragma unroll
    for (int mt = 0; mt < 4; ++mt) {
      #pragma unroll
      for (int r = 0; r < 4; ++r) {
        const int row = m0 + wave*64 + mt*16 + quad*4 + r;
        oproj[(size_t)row * 64 + col] = f2bb(acc[mt][nt][r] + bc);
      }
    }
  }
}

// ---------------------------------------------------------------------------
// adjacency GEMM via MFMA, split-K(8) (R14 version: LDS-staged A, bf16 B)
// ---------------------------------------------------------------------------
__global__ __launch_bounds__(256) void gemm_adj_mfma(const u16* __restrict__ Amat,
                                                     const u16* __restrict__ BmatB,
                                                     float* __restrict__ part)
{
  constexpr int K = CNc, Kc = CNc/8;   // 1568 = 49*32
  __shared__ u16 As[64 * 40];
  __shared__ u16 Bs[64 * 40];
  const int t = threadIdx.x;
  const int m0 = blockIdx.y * 64, n0 = blockIdx.x * 64;
  const int kbeg = blockIdx.z * Kc;
  const int wave = t >> 6, lane = t & 63;
  const int mi = lane & 15, quad = lane >> 4;
  const int srow = t >> 2, sc8 = (t & 3) * 8;

  v4f acc[4];
  #pragma unroll
  for (int b = 0; b < 4; ++b) acc[b] = (v4f){0.f, 0.f, 0.f, 0.f};

  for (int kt = 0; kt < Kc; kt += 32) {
    {
      uint4 ua = *reinterpret_cast<const uint4*>(Amat + (size_t)(m0 + srow) * K + kbeg + kt + sc8);
      *reinterpret_cast<uint4*>(&As[srow*40 + sc8]) = ua;
      uint4 ub = *reinterpret_cast<const uint4*>(BmatB + (size_t)(n0 + srow) * K + kbeg + kt + sc8);
      *reinterpret_cast<uint4*>(&Bs[srow*40 + sc8]) = ub;
    }
    __syncthreads();
    v8s af = *reinterpret_cast<const v8s*>(&As[(wave*16 + mi)*40 + quad*8]);
    v8s bf[4];
    #pragma unroll
    for (int nt = 0; nt < 4; ++nt)
      bf[nt] = *reinterpret_cast<const v8s*>(&Bs[(nt*16 + mi)*40 + quad*8]);
    #pragma unroll
    for (int nt = 0; nt < 4; ++nt)
      acc[nt] = __builtin_amdgcn_mfma_f32_16x16x32_bf16(af, bf[nt], acc[nt], 0, 0, 0);
    __syncthreads();
  }

  const size_t zoff = (size_t)blockIdx.z * B3c * 256;
  #pragma unroll
  for (int nt = 0; nt < 4; ++nt) {
    const int col = n0 + nt*16 + mi;
    #pragma unroll
    for (int r = 0; r < 4; ++r) {
      const int row = m0 + wave*16 + quad*4 + r;
      part[zoff + (size_t)row * 256 + col] = acc[nt][r];
    }
  }
}

__global__ __launch_bounds__(256) void reduce_bias_kernel(const float* __restrict__ part,
                                                          const float* __restrict__ bias,
                                                          float* __restrict__ outp)
{
  const int idx = blockIdx.x * 256 + threadIdx.x;   // 768*256 exact
  const int n = idx & 255;
  float acc = bias[n];
  #pragma unroll
  for (int s = 0; s < 8; ++s) acc += part[(size_t)s * B3c * 256 + idx];
  outp[idx] = acc;                                  // fp32 output
}

// ---------------------------------------------------------------------------
extern "C" void kernel_launch(void* const* d_in, const int* in_sizes, int n_in,
                              void* d_out, int out_size, void* d_ws, size_t ws_size,
                              hipStream_t stream)
{
  auto in = [&](int i){ return reinterpret_cast<const float*>(d_in[i]); };
  const float *X = in(0), *We = in(1), *be = in(2), *Wq = in(3), *Wp = in(4), *bp = in(5),
              *dww = in(6), *dwb = in(7), *anb = in(8), *nab = in(9), *ahb = in(10), *awb = in(11),
              *hab = in(12), *wab = in(13), *Wadj = in(14), *badj = in(15),
              *W1 = in(16), *b1 = in(17), *W2 = in(18), *b2 = in(19);
  float* out = reinterpret_cast<float*>(d_out);
  char* w = reinterpret_cast<char*>(d_ws);

  const size_t TOK = (size_t)B3c * CNc;          // 9,633,792 elements
  u16* xt = reinterpret_cast<u16*>(w);            // slot0: xt -> o -> oproj
  u16* qh = reinterpret_cast<u16*>(w + TOK*2);    // slot1: We_bf[0:] -> q head-major -> U
  u16* kh = reinterpret_cast<u16*>(w + TOK*4);    // slot2: We_bf[..] -> k head-major -> part
  u16* vb = reinterpret_cast<u16*>(w + TOK*6);    // slot3: X_bf -> v token-major -> H
  float* pb = reinterpret_cast<float*>(w + TOK*8);
  float* ab = pb + NHc*Ac*Nc;
  u16* WadjB = reinterpret_cast<u16*>(ab + NHc*Ac*Nc);   // 6.4 MB, persistent
  u16* WeB = qh;                                  // 32.1 MB spans slot1+slot2 (38.5 MB)
  u16* XB  = vb;                                  // 2.0 MB in slot3
  u16* U = qh;                                    // alias: qh dead after attn
  float* part = reinterpret_cast<float*>(kh);     // alias: kh dead after attn
  u16* H = vb;                                    // alias: vb dead after dwc
  // total ws use: ~86.0 MB (<= 93.6 MB proven in R3)

  conv_bf16_kernel<<<dim3((WeN + XN + WadjN)/(256*8)), 256, 0, stream>>>(We, X, Wadj, WeB, XB, WadjB);
  gemm_embed_bf16<<<dim3(CNc/128, B3c/128), 256, 0, stream>>>(XB, WeB, be, xt);
  qkv_mfma<<<dim3((B3c*Nc)/256, 3), 256, 0, stream>>>(xt, Wq, qh, kh, vb);
  bias_kernel<<<dim3((2*NHc*Ac*Nc + 255)/256), 256, 0, stream>>>(anb, nab, ahb, awb, hab, wab, pb, ab);
  attn_kernel<<<dim3(B3c*NHc), 256, 0, stream>>>(qh, kh, vb, pb, ab, xt /*o*/);
  dwc_kernel<<<dim3(B3c), 256, 0, stream>>>(xt /*o*/, vb, dww, dwb, U);
  proj_mfma<<<dim3((B3c*Nc)/256), 256, 0, stream>>>(U, Wp, bp, xt /*oproj*/);
  gemm_adj_mfma<<<dim3(256/64, B3c/64, 8), 256, 0, stream>>>(xt /*oproj*/, WadjB, part);
  reduce_bias_kernel<<<dim3((B3c*256)/256), 256, 0, stream>>>(part, badj, out + 3*Bn*128);
  gemm_f32_mfma<Dd, 256, true><<<dim3(B3c/128, 2), 256, 0, stream>>>(X, W1, b1, H);
  mlp2_mfma<<<dim3(B3c/128), 256, 0, stream>>>(H, W2, b2, out);
}